// Round 4
// baseline (7663.072 us; speedup 1.0000x reference)
//
#include <hip/hip_runtime.h>
#include <cstdint>
#include <cstddef>

#define TT 20
#define BB 262144

// f64 packed weight layout (element offsets, in doubles). All per-part DENSE:
//   W1P [4][10][16] @ 0     W1P[p][k][o] = W1[p*16+o][k]
//   W2P [2][64][16] @ 640   W2P[p][k][o] = W2[p*16+o][k]
//   W3P [2][32][16] @ 2688  W3P[p][k][o] = W3[p*16+o][k]
//   W4T [32][16]    @ 3712  W4T[k][o]    = W4[o][k]
//   W5T [16][6]     @ 4224  W5T[k][o]    = W5[o][k]     total 4320 doubles
#define OFF_W2P 640
#define OFF_W3P 2688
#define OFF_W4T 3712
#define OFF_W5T 4224
#define W_TOTAL 4320

// workspace layout (bytes) — same 62,949,376 B budget proven in R2/R3.
#define WS_MASK_BASE 34816
#define P1_BYTES (4 * (size_t)TT * BB * 2)     // u16[4][TT][BB]  l1 spikes
#define P2_OFFSET (WS_MASK_BASE + P1_BYTES)
#define P2_BYTES (2 * (size_t)TT * BB * 2)     // u16[2][TT][BB]  l2 spikes
#define WS_NEEDED (P2_OFFSET + P2_BYTES)
#define PLANE ((size_t)TT * BB)
// P3 (l3 spikes, u16[2][TT][BB]) aliases P1 — l1 data dead after l2.

__global__ void prep_weights(const float* __restrict__ W1, const float* __restrict__ W2,
                             const float* __restrict__ W3, const float* __restrict__ W4,
                             const float* __restrict__ W5, double* __restrict__ Wd) {
  int stride = blockDim.x * gridDim.x;
  for (int idx = blockIdx.x * blockDim.x + threadIdx.x; idx < W_TOTAL; idx += stride) {
    double v;
    if (idx < OFF_W2P) {
      int j = idx;            int p = j / 160, k = (j % 160) / 16, o = j % 16;
      v = (double)W1[(p * 16 + o) * 10 + k];
    } else if (idx < OFF_W3P) {
      int j = idx - OFF_W2P;  int p = j / 1024, k = (j % 1024) / 16, o = j % 16;
      v = (double)W2[(p * 16 + o) * 64 + k];
    } else if (idx < OFF_W4T) {
      int j = idx - OFF_W3P;  int p = j / 512, k = (j % 512) / 16, o = j % 16;
      v = (double)W3[(p * 16 + o) * 32 + k];
    } else if (idx < OFF_W5T) {
      int j = idx - OFF_W4T;  int k = j / 16, o = j % 16; v = (double)W4[o * 32 + k];
    } else {
      int j = idx - OFF_W5T;  int k = j / 6,  o = j % 6;  v = (double)W5[o * 16 + k];
    }
    Wd[idx] = v;
  }
}

// Layer 1 (10 -> 64): block = 64 elements x 4 parts (256 thr). x staged in LDS
// once per t -> each x byte fetched from HBM exactly once (R3 fetched 2x).
// VGPR ~55 -> lb(256,8) gives 8 waves/SIMD (R3's lb(256,4) was the occupancy bug).
__global__ __launch_bounds__(256, 8) void snn_l1(const float* __restrict__ x,
                                                 const double* __restrict__ Wd,
                                                 uint16_t* __restrict__ P1) {
  const int el = threadIdx.x & 63;
  const int part = threadIdx.x >> 6;
  const int eb = blockIdx.x * 64;
  const double* __restrict__ W1P = Wd + part * 160;
  uint16_t* __restrict__ dst = P1 + (size_t)part * PLANE + (eb + el);

  __shared__ float xs[640];   // 64 elements x 10 floats = 2560 B

  double m[16];
#pragma unroll
  for (int o = 0; o < 16; ++o) m[o] = 0.0;

#pragma unroll 1
  for (int t = 0; t < TT; ++t) {
    __syncthreads();   // protect previous iteration's xs reads
    const float2* xt = (const float2*)(x + ((size_t)t * BB + eb) * 10);
    ((float2*)xs)[threadIdx.x] = xt[threadIdx.x];
    if (threadIdx.x < 64)
      ((float2*)xs)[256 + threadIdx.x] = xt[256 + threadIdx.x];
    __syncthreads();

    float xv[10];
#pragma unroll
    for (int i = 0; i < 5; ++i) {
      float2 f = ((const float2*)xs)[el * 5 + i];
      xv[2 * i] = f.x; xv[2 * i + 1] = f.y;
    }
#pragma unroll
    for (int o = 0; o < 16; ++o) {
      double sub = (m[o] > 1.0) ? 1.0 : 0.0;
      m[o] = 0.9 * m[o] - sub;
    }
#pragma unroll
    for (int k = 0; k < 10; ++k) {
      double s = (double)xv[k];
      const double* col = W1P + k * 16;
#pragma unroll
      for (int o = 0; o < 16; ++o) m[o] = fma(s, col[o], m[o]);
    }
    uint32_t msk = 0u;
#pragma unroll
    for (int o = 0; o < 16; ++o) msk |= (m[o] > 1.0) ? (1u << o) : 0u;
    dst[(size_t)t * BB] = (uint16_t)msk;
  }
}

// Layer 2 (64 -> 32): 2 parts x 16 outputs, grid 2048, packed dense weights.
__global__ __launch_bounds__(256, 8) void snn_l2(const double* __restrict__ Wd,
                                                 const uint16_t* __restrict__ P1,
                                                 uint16_t* __restrict__ P2) {
  const int part = blockIdx.x & 1;
  const int e = (blockIdx.x >> 1) * 256 + threadIdx.x;
  const double* __restrict__ W2P = Wd + OFF_W2P + part * 1024;
  const uint16_t* __restrict__ src = P1 + e;
  uint16_t* __restrict__ dst = P2 + (size_t)part * PLANE + e;

  double m[16];
#pragma unroll
  for (int o = 0; o < 16; ++o) m[o] = 0.0;

#pragma unroll 1
  for (int t = 0; t < TT; ++t) {
    const size_t off = (size_t)t * BB;
    uint32_t blo = (uint32_t)src[off] | ((uint32_t)src[off + PLANE] << 16);
    uint32_t bhi = (uint32_t)src[off + 2 * PLANE] | ((uint32_t)src[off + 3 * PLANE] << 16);
#pragma unroll
    for (int o = 0; o < 16; ++o) {
      double sub = (m[o] > 1.0) ? 1.0 : 0.0;
      m[o] = 0.9 * m[o] - sub;
    }
    {
      const double* col = W2P;
      uint32_t b = blo;
      for (int k = 0; k < 32; ++k) {
        double s = (double)(b & 1u);
        b >>= 1;
#pragma unroll
        for (int o = 0; o < 16; ++o) m[o] = fma(s, col[o], m[o]);
        col += 16;
      }
      b = bhi;
      for (int k = 0; k < 32; ++k) {
        double s = (double)(b & 1u);
        b >>= 1;
#pragma unroll
        for (int o = 0; o < 16; ++o) m[o] = fma(s, col[o], m[o]);
        col += 16;
      }
    }
    uint32_t msk = 0u;
#pragma unroll
    for (int o = 0; o < 16; ++o) msk |= (m[o] > 1.0) ? (1u << o) : 0u;
    dst[off] = (uint16_t)msk;
  }
}

// Layer 3 (32 -> 32): 2 parts x 16 outputs, grid 2048, packed dense weights.
__global__ __launch_bounds__(256, 8) void snn_l3(const double* __restrict__ Wd,
                                                 const uint16_t* __restrict__ P2,
                                                 uint16_t* __restrict__ P3) {
  const int part = blockIdx.x & 1;
  const int e = (blockIdx.x >> 1) * 256 + threadIdx.x;
  const double* __restrict__ W3P = Wd + OFF_W3P + part * 512;
  const uint16_t* __restrict__ src = P2 + e;
  uint16_t* __restrict__ dst = P3 + (size_t)part * PLANE + e;

  double m[16];
#pragma unroll
  for (int o = 0; o < 16; ++o) m[o] = 0.0;

#pragma unroll 1
  for (int t = 0; t < TT; ++t) {
    const size_t off = (size_t)t * BB;
    uint32_t bits = (uint32_t)src[off] | ((uint32_t)src[off + PLANE] << 16);
#pragma unroll
    for (int o = 0; o < 16; ++o) {
      double sub = (m[o] > 1.0) ? 1.0 : 0.0;
      m[o] = 0.9 * m[o] - sub;
    }
    {
      const double* col = W3P;
      uint32_t b = bits;
      for (int k = 0; k < 32; ++k) {
        double s = (double)(b & 1u);
        b >>= 1;
#pragma unroll
        for (int o = 0; o < 16; ++o) m[o] = fma(s, col[o], m[o]);
        col += 16;
      }
    }
    uint32_t msk = 0u;
#pragma unroll
    for (int o = 0; o < 16; ++o) msk |= (m[o] > 1.0) ? (1u << o) : 0u;
    dst[off] = (uint16_t)msk;
  }
}

// Layers 4+5 fused (32 -> 16 -> 6): one thread per element, grid 1024.
// State 22 doubles (~70 VGPR) -> lb(256,4). Saves one launch + 47 MB mask IO.
__global__ __launch_bounds__(256, 4) void snn_l45(const double* __restrict__ Wd,
                                                  const uint16_t* __restrict__ P3,
                                                  float* __restrict__ out) {
  const int e = blockIdx.x * 256 + threadIdx.x;
  const double* __restrict__ W4T = Wd + OFF_W4T;
  const double* __restrict__ W5T = Wd + OFF_W5T;
  const uint16_t* __restrict__ src = P3 + e;

  double m4[16], m5[6];
#pragma unroll
  for (int o = 0; o < 16; ++o) m4[o] = 0.0;
#pragma unroll
  for (int o = 0; o < 6; ++o) m5[o] = 0.0;

#pragma unroll 1
  for (int t = 0; t < TT; ++t) {
    const size_t off = (size_t)t * BB;
    uint32_t bits = (uint32_t)src[off] | ((uint32_t)src[off + PLANE] << 16);

#pragma unroll
    for (int o = 0; o < 16; ++o) {
      double sub = (m4[o] > 1.0) ? 1.0 : 0.0;
      m4[o] = 0.9 * m4[o] - sub;
    }
    {
      const double* col = W4T;
      uint32_t b = bits;
      for (int k = 0; k < 32; ++k) {
        double s = (double)(b & 1u);
        b >>= 1;
#pragma unroll
        for (int o = 0; o < 16; ++o) m4[o] = fma(s, col[o], m4[o]);
        col += 16;
      }
    }
    uint32_t msk4 = 0u;
#pragma unroll
    for (int o = 0; o < 16; ++o) msk4 |= (m4[o] > 1.0) ? (1u << o) : 0u;

#pragma unroll
    for (int o = 0; o < 6; ++o) {
      double sub = (m5[o] > 1.0) ? 1.0 : 0.0;
      m5[o] = 0.9 * m5[o] - sub;
    }
    {
      const double* col = W5T;
      uint32_t b = msk4;
      for (int k = 0; k < 16; ++k) {
        double s = (double)(b & 1u);
        b >>= 1;
#pragma unroll
        for (int o = 0; o < 6; ++o) m5[o] = fma(s, col[o], m5[o]);
        col += 6;
      }
    }

    float ov[6];
#pragma unroll
    for (int o = 0; o < 6; ++o) ov[o] = (m5[o] > 1.0) ? 1.0f : 0.0f;
    float* op = out + ((size_t)t * BB + e) * 6;
    ((float2*)op)[0] = make_float2(ov[0], ov[1]);
    ((float2*)op)[1] = make_float2(ov[2], ov[3]);
    ((float2*)op)[2] = make_float2(ov[4], ov[5]);
  }
}

// ---------------- fallback: monolithic kernel (ws too small; packed layout) ----------------

__global__ __launch_bounds__(256, 1) void snn_f64(const float* __restrict__ x,
                                                  const double* __restrict__ Wd,
                                                  float* __restrict__ out) {
  const int e = blockIdx.x * blockDim.x + threadIdx.x;

  double m1[64], m2[32], m3[32], m4[16], m5[6];
#pragma unroll
  for (int o = 0; o < 64; ++o) m1[o] = 0.0;
#pragma unroll
  for (int o = 0; o < 32; ++o) m2[o] = 0.0;
#pragma unroll
  for (int o = 0; o < 32; ++o) m3[o] = 0.0;
#pragma unroll
  for (int o = 0; o < 16; ++o) m4[o] = 0.0;
#pragma unroll
  for (int o = 0; o < 6; ++o) m5[o] = 0.0;

#pragma unroll 1
  for (int t = 0; t < TT; ++t) {
    const float* xp = x + ((size_t)t * BB + e) * 10;
    float xv[10];
#pragma unroll
    for (int i = 0; i < 5; ++i) {
      float2 f = ((const float2*)xp)[i];
      xv[2 * i] = f.x; xv[2 * i + 1] = f.y;
    }
#pragma unroll
    for (int o = 0; o < 64; ++o) {
      double sub = (m1[o] > 1.0) ? 1.0 : 0.0;
      m1[o] = 0.9 * m1[o] - sub;
    }
#pragma unroll
    for (int p = 0; p < 4; ++p) {
#pragma unroll
      for (int k = 0; k < 10; ++k) {
        double s = (double)xv[k];
        const double* col = Wd + p * 160 + k * 16;
#pragma unroll
        for (int o = 0; o < 16; ++o) m1[p * 16 + o] = fma(s, col[o], m1[p * 16 + o]);
      }
    }
    unsigned long long msk1 = 0ull;
#pragma unroll
    for (int o = 0; o < 64; ++o) msk1 |= (m1[o] > 1.0) ? (1ull << o) : 0ull;

#pragma unroll
    for (int o = 0; o < 32; ++o) {
      double sub = (m2[o] > 1.0) ? 1.0 : 0.0;
      m2[o] = 0.9 * m2[o] - sub;
    }
#pragma unroll
    for (int p = 0; p < 2; ++p) {
      unsigned long long b = msk1;
      const double* col = Wd + OFF_W2P + p * 1024;
      for (int k = 0; k < 64; ++k) {
        double s = (double)(unsigned int)(b & 1ull);
        b >>= 1;
#pragma unroll
        for (int o = 0; o < 16; ++o) m2[p * 16 + o] = fma(s, col[o], m2[p * 16 + o]);
        col += 16;
      }
    }
    unsigned int msk2 = 0u;
#pragma unroll
    for (int o = 0; o < 32; ++o) msk2 |= (m2[o] > 1.0) ? (1u << o) : 0u;

#pragma unroll
    for (int o = 0; o < 32; ++o) {
      double sub = (m3[o] > 1.0) ? 1.0 : 0.0;
      m3[o] = 0.9 * m3[o] - sub;
    }
#pragma unroll
    for (int p = 0; p < 2; ++p) {
      unsigned int b = msk2;
      const double* col = Wd + OFF_W3P + p * 512;
      for (int k = 0; k < 32; ++k) {
        double s = (double)(b & 1u);
        b >>= 1;
#pragma unroll
        for (int o = 0; o < 16; ++o) m3[p * 16 + o] = fma(s, col[o], m3[p * 16 + o]);
        col += 16;
      }
    }
    unsigned int msk3 = 0u;
#pragma unroll
    for (int o = 0; o < 32; ++o) msk3 |= (m3[o] > 1.0) ? (1u << o) : 0u;

#pragma unroll
    for (int o = 0; o < 16; ++o) {
      double sub = (m4[o] > 1.0) ? 1.0 : 0.0;
      m4[o] = 0.9 * m4[o] - sub;
    }
    {
      unsigned int b = msk3;
      const double* col = Wd + OFF_W4T;
      for (int k = 0; k < 32; ++k) {
        double s = (double)(b & 1u);
        b >>= 1;
#pragma unroll
        for (int o = 0; o < 16; ++o) m4[o] = fma(s, col[o], m4[o]);
        col += 16;
      }
    }
    unsigned int msk4 = 0u;
#pragma unroll
    for (int o = 0; o < 16; ++o) msk4 |= (m4[o] > 1.0) ? (1u << o) : 0u;

#pragma unroll
    for (int o = 0; o < 6; ++o) {
      double sub = (m5[o] > 1.0) ? 1.0 : 0.0;
      m5[o] = 0.9 * m5[o] - sub;
    }
    {
      unsigned int b = msk4;
      const double* col = Wd + OFF_W5T;
      for (int k = 0; k < 16; ++k) {
        double s = (double)(b & 1u);
        b >>= 1;
#pragma unroll
        for (int o = 0; o < 6; ++o) m5[o] = fma(s, col[o], m5[o]);
        col += 6;
      }
    }

    float ov[6];
#pragma unroll
    for (int o = 0; o < 6; ++o) ov[o] = (m5[o] > 1.0) ? 1.0f : 0.0f;
    float* op = out + ((size_t)t * BB + e) * 6;
    ((float2*)op)[0] = make_float2(ov[0], ov[1]);
    ((float2*)op)[1] = make_float2(ov[2], ov[3]);
    ((float2*)op)[2] = make_float2(ov[4], ov[5]);
  }
}

extern "C" void kernel_launch(void* const* d_in, const int* in_sizes, int n_in,
                              void* d_out, int out_size, void* d_ws, size_t ws_size,
                              hipStream_t stream) {
  const float* x  = (const float*)d_in[0];
  const float* W1 = (const float*)d_in[1];
  const float* W2 = (const float*)d_in[2];
  const float* W3 = (const float*)d_in[3];
  const float* W4 = (const float*)d_in[4];
  const float* W5 = (const float*)d_in[5];
  float* out = (float*)d_out;
  double* Wd = (double*)d_ws;

  prep_weights<<<17, 256, 0, stream>>>(W1, W2, W3, W4, W5, Wd);

  if (ws_size >= WS_NEEDED) {
    char* base = (char*)d_ws;
    uint16_t* P1 = (uint16_t*)(base + WS_MASK_BASE);
    uint16_t* P2 = (uint16_t*)(base + P2_OFFSET);
    uint16_t* P3 = (uint16_t*)(base + WS_MASK_BASE);  // aliases P1 (dead after l2)
    snn_l1<<<4096, 256, 0, stream>>>(x, Wd, P1);
    snn_l2<<<2048, 256, 0, stream>>>(Wd, P1, P2);
    snn_l3<<<2048, 256, 0, stream>>>(Wd, P2, P3);
    snn_l45<<<1024, 256, 0, stream>>>(Wd, P3, out);
  } else {
    snn_f64<<<BB / 256, 256, 0, stream>>>(x, Wd, out);
  }
}

// Round 5
// 1482.864 us; speedup vs baseline: 5.1678x; 5.1678x over previous
//
#include <hip/hip_runtime.h>
#include <cstdint>
#include <cstddef>

#define TT 20
#define BB 262144

// f64 packed weight layout (element offsets, in doubles). All per-part DENSE:
//   W1P [4][10][16] @ 0     W1P[p][k][o] = W1[p*16+o][k]
//   W2P [2][64][16] @ 640   W2P[p][k][o] = W2[p*16+o][k]
//   W3P [2][32][16] @ 2688  W3P[p][k][o] = W3[p*16+o][k]
//   W4T [32][16]    @ 3712  W4T[k][o]    = W4[o][k]
//   W5T [16][6]     @ 4224  W5T[k][o]    = W5[o][k]     total 4320 doubles
#define OFF_W2P 640
#define OFF_W3P 2688
#define OFF_W4T 3712
#define OFF_W5T 4224
#define W_TOTAL 4320

// workspace layout (bytes) — same 62,949,376 B budget proven in R2-R4.
#define WS_MASK_BASE 34816
#define P1_BYTES (4 * (size_t)TT * BB * 2)     // u16[4][TT][BB]  l1 spikes
#define P2_OFFSET (WS_MASK_BASE + P1_BYTES)
#define P2_BYTES (2 * (size_t)TT * BB * 2)     // u16[2][TT][BB]  l2 spikes
#define WS_NEEDED (P2_OFFSET + P2_BYTES)
#define PLANE ((size_t)TT * BB)
// P3 (l3 spikes, u16[2][TT][BB]) aliases P1 — l1 data dead after l2.

__global__ void prep_weights(const float* __restrict__ W1, const float* __restrict__ W2,
                             const float* __restrict__ W3, const float* __restrict__ W4,
                             const float* __restrict__ W5, double* __restrict__ Wd) {
  int stride = blockDim.x * gridDim.x;
  for (int idx = blockIdx.x * blockDim.x + threadIdx.x; idx < W_TOTAL; idx += stride) {
    double v;
    if (idx < OFF_W2P) {
      int j = idx;            int p = j / 160, k = (j % 160) / 16, o = j % 16;
      v = (double)W1[(p * 16 + o) * 10 + k];
    } else if (idx < OFF_W3P) {
      int j = idx - OFF_W2P;  int p = j / 1024, k = (j % 1024) / 16, o = j % 16;
      v = (double)W2[(p * 16 + o) * 64 + k];
    } else if (idx < OFF_W4T) {
      int j = idx - OFF_W3P;  int p = j / 512, k = (j % 512) / 16, o = j % 16;
      v = (double)W3[(p * 16 + o) * 32 + k];
    } else if (idx < OFF_W5T) {
      int j = idx - OFF_W4T;  int k = j / 16, o = j % 16; v = (double)W4[o * 32 + k];
    } else {
      int j = idx - OFF_W5T;  int k = j / 6,  o = j % 6;  v = (double)W5[o * 16 + k];
    }
    Wd[idx] = v;
  }
}

// Layer 1 (10 -> 64): 4 parts x 16 outputs, part = blockIdx.x & 3 (WAVE-UNIFORM —
// R4's threadIdx-derived part broke the scalar weight path: SGPR 112->16,
// 16.7 GB of per-lane VMEM weight traffic, VALUBusy 2.4%). Packed dense W1P.
// lb(256,8): R3's lb(256,4) capped occupancy at 51%.
__global__ __launch_bounds__(256, 8) void snn_l1(const float* __restrict__ x,
                                                 const double* __restrict__ Wd,
                                                 uint16_t* __restrict__ P1) {
  const int part = blockIdx.x & 3;                       // scalar (block-uniform)
  const int e = (blockIdx.x >> 2) * 256 + threadIdx.x;
  const double* __restrict__ W1P = Wd + part * 160;      // SGPR base -> s_load
  uint16_t* __restrict__ dst = P1 + (size_t)part * PLANE + e;

  double m[16];
#pragma unroll
  for (int o = 0; o < 16; ++o) m[o] = 0.0;

#pragma unroll 1
  for (int t = 0; t < TT; ++t) {
    const float* xp = x + ((size_t)t * BB + e) * 10;
    float xv[10];
#pragma unroll
    for (int i = 0; i < 5; ++i) {
      float2 f = ((const float2*)xp)[i];
      xv[2 * i] = f.x; xv[2 * i + 1] = f.y;
    }
#pragma unroll
    for (int o = 0; o < 16; ++o) {
      double sub = (m[o] > 1.0) ? 1.0 : 0.0;
      m[o] = 0.9 * m[o] - sub;
    }
#pragma unroll
    for (int k = 0; k < 10; ++k) {
      double s = (double)xv[k];
      const double* col = W1P + k * 16;
#pragma unroll
      for (int o = 0; o < 16; ++o) m[o] = fma(s, col[o], m[o]);
    }
    uint32_t msk = 0u;
#pragma unroll
    for (int o = 0; o < 16; ++o) msk |= (m[o] > 1.0) ? (1u << o) : 0u;
    dst[(size_t)t * BB] = (uint16_t)msk;
  }
}

// Layer 2 (64 -> 32): 2 parts x 16 outputs, grid 2048, packed dense weights.
// (R4-measured good: part blockIdx-uniform, lb(256,8).)
__global__ __launch_bounds__(256, 8) void snn_l2(const double* __restrict__ Wd,
                                                 const uint16_t* __restrict__ P1,
                                                 uint16_t* __restrict__ P2) {
  const int part = blockIdx.x & 1;
  const int e = (blockIdx.x >> 1) * 256 + threadIdx.x;
  const double* __restrict__ W2P = Wd + OFF_W2P + part * 1024;
  const uint16_t* __restrict__ src = P1 + e;
  uint16_t* __restrict__ dst = P2 + (size_t)part * PLANE + e;

  double m[16];
#pragma unroll
  for (int o = 0; o < 16; ++o) m[o] = 0.0;

#pragma unroll 1
  for (int t = 0; t < TT; ++t) {
    const size_t off = (size_t)t * BB;
    uint32_t blo = (uint32_t)src[off] | ((uint32_t)src[off + PLANE] << 16);
    uint32_t bhi = (uint32_t)src[off + 2 * PLANE] | ((uint32_t)src[off + 3 * PLANE] << 16);
#pragma unroll
    for (int o = 0; o < 16; ++o) {
      double sub = (m[o] > 1.0) ? 1.0 : 0.0;
      m[o] = 0.9 * m[o] - sub;
    }
    {
      const double* col = W2P;
      uint32_t b = blo;
      for (int k = 0; k < 32; ++k) {
        double s = (double)(b & 1u);
        b >>= 1;
#pragma unroll
        for (int o = 0; o < 16; ++o) m[o] = fma(s, col[o], m[o]);
        col += 16;
      }
      b = bhi;
      for (int k = 0; k < 32; ++k) {
        double s = (double)(b & 1u);
        b >>= 1;
#pragma unroll
        for (int o = 0; o < 16; ++o) m[o] = fma(s, col[o], m[o]);
        col += 16;
      }
    }
    uint32_t msk = 0u;
#pragma unroll
    for (int o = 0; o < 16; ++o) msk |= (m[o] > 1.0) ? (1u << o) : 0u;
    dst[off] = (uint16_t)msk;
  }
}

// Layer 3 (32 -> 32): 2 parts x 16 outputs, grid 2048, packed dense weights.
__global__ __launch_bounds__(256, 8) void snn_l3(const double* __restrict__ Wd,
                                                 const uint16_t* __restrict__ P2,
                                                 uint16_t* __restrict__ P3) {
  const int part = blockIdx.x & 1;
  const int e = (blockIdx.x >> 1) * 256 + threadIdx.x;
  const double* __restrict__ W3P = Wd + OFF_W3P + part * 512;
  const uint16_t* __restrict__ src = P2 + e;
  uint16_t* __restrict__ dst = P3 + (size_t)part * PLANE + e;

  double m[16];
#pragma unroll
  for (int o = 0; o < 16; ++o) m[o] = 0.0;

#pragma unroll 1
  for (int t = 0; t < TT; ++t) {
    const size_t off = (size_t)t * BB;
    uint32_t bits = (uint32_t)src[off] | ((uint32_t)src[off + PLANE] << 16);
#pragma unroll
    for (int o = 0; o < 16; ++o) {
      double sub = (m[o] > 1.0) ? 1.0 : 0.0;
      m[o] = 0.9 * m[o] - sub;
    }
    {
      const double* col = W3P;
      uint32_t b = bits;
      for (int k = 0; k < 32; ++k) {
        double s = (double)(b & 1u);
        b >>= 1;
#pragma unroll
        for (int o = 0; o < 16; ++o) m[o] = fma(s, col[o], m[o]);
        col += 16;
      }
    }
    uint32_t msk = 0u;
#pragma unroll
    for (int o = 0; o < 16; ++o) msk |= (m[o] > 1.0) ? (1u << o) : 0u;
    dst[off] = (uint16_t)msk;
  }
}

// Layers 4+5 fused (32 -> 16 -> 6): one thread per element, grid 1024.
__global__ __launch_bounds__(256, 4) void snn_l45(const double* __restrict__ Wd,
                                                  const uint16_t* __restrict__ P3,
                                                  float* __restrict__ out) {
  const int e = blockIdx.x * 256 + threadIdx.x;
  const double* __restrict__ W4T = Wd + OFF_W4T;
  const double* __restrict__ W5T = Wd + OFF_W5T;
  const uint16_t* __restrict__ src = P3 + e;

  double m4[16], m5[6];
#pragma unroll
  for (int o = 0; o < 16; ++o) m4[o] = 0.0;
#pragma unroll
  for (int o = 0; o < 6; ++o) m5[o] = 0.0;

#pragma unroll 1
  for (int t = 0; t < TT; ++t) {
    const size_t off = (size_t)t * BB;
    uint32_t bits = (uint32_t)src[off] | ((uint32_t)src[off + PLANE] << 16);

#pragma unroll
    for (int o = 0; o < 16; ++o) {
      double sub = (m4[o] > 1.0) ? 1.0 : 0.0;
      m4[o] = 0.9 * m4[o] - sub;
    }
    {
      const double* col = W4T;
      uint32_t b = bits;
      for (int k = 0; k < 32; ++k) {
        double s = (double)(b & 1u);
        b >>= 1;
#pragma unroll
        for (int o = 0; o < 16; ++o) m4[o] = fma(s, col[o], m4[o]);
        col += 16;
      }
    }
    uint32_t msk4 = 0u;
#pragma unroll
    for (int o = 0; o < 16; ++o) msk4 |= (m4[o] > 1.0) ? (1u << o) : 0u;

#pragma unroll
    for (int o = 0; o < 6; ++o) {
      double sub = (m5[o] > 1.0) ? 1.0 : 0.0;
      m5[o] = 0.9 * m5[o] - sub;
    }
    {
      const double* col = W5T;
      uint32_t b = msk4;
      for (int k = 0; k < 16; ++k) {
        double s = (double)(b & 1u);
        b >>= 1;
#pragma unroll
        for (int o = 0; o < 6; ++o) m5[o] = fma(s, col[o], m5[o]);
        col += 6;
      }
    }

    float ov[6];
#pragma unroll
    for (int o = 0; o < 6; ++o) ov[o] = (m5[o] > 1.0) ? 1.0f : 0.0f;
    float* op = out + ((size_t)t * BB + e) * 6;
    ((float2*)op)[0] = make_float2(ov[0], ov[1]);
    ((float2*)op)[1] = make_float2(ov[2], ov[3]);
    ((float2*)op)[2] = make_float2(ov[4], ov[5]);
  }
}

// ---------------- fallback: monolithic kernel (ws too small; packed layout) ----------------

__global__ __launch_bounds__(256, 1) void snn_f64(const float* __restrict__ x,
                                                  const double* __restrict__ Wd,
                                                  float* __restrict__ out) {
  const int e = blockIdx.x * blockDim.x + threadIdx.x;

  double m1[64], m2[32], m3[32], m4[16], m5[6];
#pragma unroll
  for (int o = 0; o < 64; ++o) m1[o] = 0.0;
#pragma unroll
  for (int o = 0; o < 32; ++o) m2[o] = 0.0;
#pragma unroll
  for (int o = 0; o < 32; ++o) m3[o] = 0.0;
#pragma unroll
  for (int o = 0; o < 16; ++o) m4[o] = 0.0;
#pragma unroll
  for (int o = 0; o < 6; ++o) m5[o] = 0.0;

#pragma unroll 1
  for (int t = 0; t < TT; ++t) {
    const float* xp = x + ((size_t)t * BB + e) * 10;
    float xv[10];
#pragma unroll
    for (int i = 0; i < 5; ++i) {
      float2 f = ((const float2*)xp)[i];
      xv[2 * i] = f.x; xv[2 * i + 1] = f.y;
    }
#pragma unroll
    for (int o = 0; o < 64; ++o) {
      double sub = (m1[o] > 1.0) ? 1.0 : 0.0;
      m1[o] = 0.9 * m1[o] - sub;
    }
#pragma unroll
    for (int p = 0; p < 4; ++p) {
#pragma unroll
      for (int k = 0; k < 10; ++k) {
        double s = (double)xv[k];
        const double* col = Wd + p * 160 + k * 16;
#pragma unroll
        for (int o = 0; o < 16; ++o) m1[p * 16 + o] = fma(s, col[o], m1[p * 16 + o]);
      }
    }
    unsigned long long msk1 = 0ull;
#pragma unroll
    for (int o = 0; o < 64; ++o) msk1 |= (m1[o] > 1.0) ? (1ull << o) : 0ull;

#pragma unroll
    for (int o = 0; o < 32; ++o) {
      double sub = (m2[o] > 1.0) ? 1.0 : 0.0;
      m2[o] = 0.9 * m2[o] - sub;
    }
#pragma unroll
    for (int p = 0; p < 2; ++p) {
      unsigned long long b = msk1;
      const double* col = Wd + OFF_W2P + p * 1024;
      for (int k = 0; k < 64; ++k) {
        double s = (double)(unsigned int)(b & 1ull);
        b >>= 1;
#pragma unroll
        for (int o = 0; o < 16; ++o) m2[p * 16 + o] = fma(s, col[o], m2[p * 16 + o]);
        col += 16;
      }
    }
    unsigned int msk2 = 0u;
#pragma unroll
    for (int o = 0; o < 32; ++o) msk2 |= (m2[o] > 1.0) ? (1u << o) : 0u;

#pragma unroll
    for (int o = 0; o < 32; ++o) {
      double sub = (m3[o] > 1.0) ? 1.0 : 0.0;
      m3[o] = 0.9 * m3[o] - sub;
    }
#pragma unroll
    for (int p = 0; p < 2; ++p) {
      unsigned int b = msk2;
      const double* col = Wd + OFF_W3P + p * 512;
      for (int k = 0; k < 32; ++k) {
        double s = (double)(b & 1u);
        b >>= 1;
#pragma unroll
        for (int o = 0; o < 16; ++o) m3[p * 16 + o] = fma(s, col[o], m3[p * 16 + o]);
        col += 16;
      }
    }
    unsigned int msk3 = 0u;
#pragma unroll
    for (int o = 0; o < 32; ++o) msk3 |= (m3[o] > 1.0) ? (1u << o) : 0u;

#pragma unroll
    for (int o = 0; o < 16; ++o) {
      double sub = (m4[o] > 1.0) ? 1.0 : 0.0;
      m4[o] = 0.9 * m4[o] - sub;
    }
    {
      unsigned int b = msk3;
      const double* col = Wd + OFF_W4T;
      for (int k = 0; k < 32; ++k) {
        double s = (double)(b & 1u);
        b >>= 1;
#pragma unroll
        for (int o = 0; o < 16; ++o) m4[o] = fma(s, col[o], m4[o]);
        col += 16;
      }
    }
    unsigned int msk4 = 0u;
#pragma unroll
    for (int o = 0; o < 16; ++o) msk4 |= (m4[o] > 1.0) ? (1u << o) : 0u;

#pragma unroll
    for (int o = 0; o < 6; ++o) {
      double sub = (m5[o] > 1.0) ? 1.0 : 0.0;
      m5[o] = 0.9 * m5[o] - sub;
    }
    {
      unsigned int b = msk4;
      const double* col = Wd + OFF_W5T;
      for (int k = 0; k < 16; ++k) {
        double s = (double)(b & 1u);
        b >>= 1;
#pragma unroll
        for (int o = 0; o < 6; ++o) m5[o] = fma(s, col[o], m5[o]);
        col += 6;
      }
    }

    float ov[6];
#pragma unroll
    for (int o = 0; o < 6; ++o) ov[o] = (m5[o] > 1.0) ? 1.0f : 0.0f;
    float* op = out + ((size_t)t * BB + e) * 6;
    ((float2*)op)[0] = make_float2(ov[0], ov[1]);
    ((float2*)op)[1] = make_float2(ov[2], ov[3]);
    ((float2*)op)[2] = make_float2(ov[4], ov[5]);
  }
}

extern "C" void kernel_launch(void* const* d_in, const int* in_sizes, int n_in,
                              void* d_out, int out_size, void* d_ws, size_t ws_size,
                              hipStream_t stream) {
  const float* x  = (const float*)d_in[0];
  const float* W1 = (const float*)d_in[1];
  const float* W2 = (const float*)d_in[2];
  const float* W3 = (const float*)d_in[3];
  const float* W4 = (const float*)d_in[4];
  const float* W5 = (const float*)d_in[5];
  float* out = (float*)d_out;
  double* Wd = (double*)d_ws;

  prep_weights<<<17, 256, 0, stream>>>(W1, W2, W3, W4, W5, Wd);

  if (ws_size >= WS_NEEDED) {
    char* base = (char*)d_ws;
    uint16_t* P1 = (uint16_t*)(base + WS_MASK_BASE);
    uint16_t* P2 = (uint16_t*)(base + P2_OFFSET);
    uint16_t* P3 = (uint16_t*)(base + WS_MASK_BASE);  // aliases P1 (dead after l2)
    snn_l1<<<4096, 256, 0, stream>>>(x, Wd, P1);
    snn_l2<<<2048, 256, 0, stream>>>(Wd, P1, P2);
    snn_l3<<<2048, 256, 0, stream>>>(Wd, P2, P3);
    snn_l45<<<1024, 256, 0, stream>>>(Wd, P3, out);
  } else {
    snn_f64<<<BB / 256, 256, 0, stream>>>(x, Wd, out);
  }
}

// Round 6
// 1471.022 us; speedup vs baseline: 5.2094x; 1.0081x over previous
//
#include <hip/hip_runtime.h>
#include <cstdint>
#include <cstddef>

#define TT 20
#define BB 262144

// f64 packed weight layout (element offsets, in doubles):
//   W1H [2][10][32] @ 0     W1H[p][k][o] = W1[p*32+o][k]   (l1: 2 parts x 32 out)
//   W2T [64][32]    @ 640   W2T[k][o]    = W2[o][k]        (l2: unsplit)
//   W3P [2][32][16] @ 2688  W3P[p][k][o] = W3[p*16+o][k]   (l3: 2 parts x 16 out)
//   W4T [32][16]    @ 3712  W4T[k][o]    = W4[o][k]
//   W5T [16][6]     @ 4224  W5T[k][o]    = W5[o][k]        total 4320 doubles
#define OFF_W2T 640
#define OFF_W3P 2688
#define OFF_W4T 3712
#define OFF_W5T 4224
#define W_TOTAL 4320

// workspace layout (bytes) — same 62,949,376 B budget proven in R2-R5.
//   Wd @ 0 (pad to 34816)
//   P1 @ 34816:    u32[TT][BB][2] = 41,943,040  (l1 spikes; [e][part] interleaved)
//   P2 @ 41977856: u32[TT][BB]    = 20,971,520  (l2 spikes)
//   P3 aliases P1: u16[TT][BB][2] = 20,971,520  (l3 spikes; l1 data dead after l2)
#define WS_MASK_BASE 34816
#define P1_BYTES (2 * (size_t)TT * BB * 4)
#define P2_OFFSET (WS_MASK_BASE + P1_BYTES)
#define P2_BYTES ((size_t)TT * BB * 4)
#define WS_NEEDED (P2_OFFSET + P2_BYTES)

__global__ void prep_weights(const float* __restrict__ W1, const float* __restrict__ W2,
                             const float* __restrict__ W3, const float* __restrict__ W4,
                             const float* __restrict__ W5, double* __restrict__ Wd) {
  int stride = blockDim.x * gridDim.x;
  for (int idx = blockIdx.x * blockDim.x + threadIdx.x; idx < W_TOTAL; idx += stride) {
    double v;
    if (idx < OFF_W2T) {
      int j = idx;            int p = j / 320, k = (j % 320) / 32, o = j % 32;
      v = (double)W1[(p * 32 + o) * 10 + k];
    } else if (idx < OFF_W3P) {
      int j = idx - OFF_W2T;  int k = j / 32, o = j % 32;
      v = (double)W2[o * 64 + k];
    } else if (idx < OFF_W4T) {
      int j = idx - OFF_W3P;  int p = j / 512, k = (j % 512) / 16, o = j % 16;
      v = (double)W3[(p * 16 + o) * 32 + k];
    } else if (idx < OFF_W5T) {
      int j = idx - OFF_W4T;  int k = j / 16, o = j % 16; v = (double)W4[o * 32 + k];
    } else {
      int j = idx - OFF_W5T;  int k = j / 6,  o = j % 6;  v = (double)W5[o * 16 + k];
    }
    Wd[idx] = v;
  }
}

// Layer 1 (10 -> 64): 2 parts x 32 outputs (R5's 4-part split was latency-bound:
// ~400 us at 640 compute-cyc/t vs 5 x-loads). part is blockIdx-derived (wave-
// uniform scalar weight path — R4 lesson). x[t+1] software-prefetched.
__global__ __launch_bounds__(256, 4) void snn_l1(const float* __restrict__ x,
                                                 const double* __restrict__ Wd,
                                                 uint32_t* __restrict__ P1) {
  const int part = blockIdx.x & 1;
  const int e = (blockIdx.x >> 1) * 256 + threadIdx.x;
  const double* __restrict__ W1H = Wd + part * 320;
  uint32_t* __restrict__ dst = P1 + (size_t)e * 2 + part;   // [t][e][part]

  double m[32];
#pragma unroll
  for (int o = 0; o < 32; ++o) m[o] = 0.0;

  float2 xf[5];
  {
    const float2* xp = (const float2*)(x + (size_t)e * 10);
#pragma unroll
    for (int i = 0; i < 5; ++i) xf[i] = xp[i];
  }

#pragma unroll 1
  for (int t = 0; t < TT; ++t) {
    float xv[10];
#pragma unroll
    for (int i = 0; i < 5; ++i) { xv[2 * i] = xf[i].x; xv[2 * i + 1] = xf[i].y; }
    if (t + 1 < TT) {
      const float2* xn = (const float2*)(x + ((size_t)(t + 1) * BB + e) * 10);
#pragma unroll
      for (int i = 0; i < 5; ++i) xf[i] = xn[i];    // prefetch next t (independent)
    }
#pragma unroll
    for (int o = 0; o < 32; ++o) {
      double sub = (m[o] > 1.0) ? 1.0 : 0.0;
      m[o] = 0.9 * m[o] - sub;
    }
#pragma unroll
    for (int k = 0; k < 10; ++k) {
      double s = (double)xv[k];
      const double* col = W1H + k * 32;
#pragma unroll
      for (int o = 0; o < 32; ++o) m[o] = fma(s, col[o], m[o]);
    }
    uint32_t msk = 0u;
#pragma unroll
    for (int o = 0; o < 32; ++o) msk |= (m[o] > 1.0) ? (1u << o) : 0u;
    dst[(size_t)t * BB * 2] = msk;
  }
}

// Layer 2 (64 -> 32): UNSPLIT — 32 outputs/thread, grid 1024. Decode amortized
// over 32 FMAs; single b64 mask load per t (P1 interleaved layout).
__global__ __launch_bounds__(256, 4) void snn_l2(const double* __restrict__ Wd,
                                                 const uint32_t* __restrict__ P1,
                                                 uint32_t* __restrict__ P2) {
  const int e = blockIdx.x * 256 + threadIdx.x;
  const double* __restrict__ W2T = Wd + OFF_W2T;
  const uint2* __restrict__ src = (const uint2*)P1 + e;     // [t][e] -> (part0, part1)
  uint32_t* __restrict__ dst = P2 + e;

  double m[32];
#pragma unroll
  for (int o = 0; o < 32; ++o) m[o] = 0.0;

#pragma unroll 1
  for (int t = 0; t < TT; ++t) {
    const size_t off = (size_t)t * BB;
    uint2 v = src[off];
#pragma unroll
    for (int o = 0; o < 32; ++o) {
      double sub = (m[o] > 1.0) ? 1.0 : 0.0;
      m[o] = 0.9 * m[o] - sub;
    }
    {
      const double* col = W2T;
      uint32_t b = v.x;                    // l1 outputs 0..31
      for (int k = 0; k < 32; ++k) {
        double s = (double)(b & 1u);
        b >>= 1;
#pragma unroll
        for (int o = 0; o < 32; ++o) m[o] = fma(s, col[o], m[o]);
        col += 32;
      }
      b = v.y;                             // l1 outputs 32..63
      for (int k = 0; k < 32; ++k) {
        double s = (double)(b & 1u);
        b >>= 1;
#pragma unroll
        for (int o = 0; o < 32; ++o) m[o] = fma(s, col[o], m[o]);
        col += 32;
      }
    }
    uint32_t msk = 0u;
#pragma unroll
    for (int o = 0; o < 32; ++o) msk |= (m[o] > 1.0) ? (1u << o) : 0u;
    dst[off] = msk;
  }
}

// Layer 3 (32 -> 32): 2 parts x 16 outputs, grid 2048 (R5-proven shape).
// Writes interleaved u16 [t][e][part] so l45 reads one u32.
__global__ __launch_bounds__(256, 8) void snn_l3(const double* __restrict__ Wd,
                                                 const uint32_t* __restrict__ P2,
                                                 uint16_t* __restrict__ P3) {
  const int part = blockIdx.x & 1;
  const int e = (blockIdx.x >> 1) * 256 + threadIdx.x;
  const double* __restrict__ W3P = Wd + OFF_W3P + part * 512;
  const uint32_t* __restrict__ src = P2 + e;
  uint16_t* __restrict__ dst = P3 + (size_t)e * 2 + part;   // [t][e][part]

  double m[16];
#pragma unroll
  for (int o = 0; o < 16; ++o) m[o] = 0.0;

#pragma unroll 1
  for (int t = 0; t < TT; ++t) {
    uint32_t bits = src[(size_t)t * BB];
#pragma unroll
    for (int o = 0; o < 16; ++o) {
      double sub = (m[o] > 1.0) ? 1.0 : 0.0;
      m[o] = 0.9 * m[o] - sub;
    }
    {
      const double* col = W3P;
      uint32_t b = bits;
      for (int k = 0; k < 32; ++k) {
        double s = (double)(b & 1u);
        b >>= 1;
#pragma unroll
        for (int o = 0; o < 16; ++o) m[o] = fma(s, col[o], m[o]);
        col += 16;
      }
    }
    uint32_t msk = 0u;
#pragma unroll
    for (int o = 0; o < 16; ++o) msk |= (m[o] > 1.0) ? (1u << o) : 0u;
    dst[(size_t)t * BB * 2] = (uint16_t)msk;
  }
}

// Layers 4+5 fused (32 -> 16 -> 6): one thread/elem, grid 1024. Single u32
// mask load per t (P3 interleaved: lo16 = l3 outputs 0..15, hi16 = 16..31).
__global__ __launch_bounds__(256, 4) void snn_l45(const double* __restrict__ Wd,
                                                  const uint32_t* __restrict__ P3u32,
                                                  float* __restrict__ out) {
  const int e = blockIdx.x * 256 + threadIdx.x;
  const double* __restrict__ W4T = Wd + OFF_W4T;
  const double* __restrict__ W5T = Wd + OFF_W5T;
  const uint32_t* __restrict__ src = P3u32 + e;

  double m4[16], m5[6];
#pragma unroll
  for (int o = 0; o < 16; ++o) m4[o] = 0.0;
#pragma unroll
  for (int o = 0; o < 6; ++o) m5[o] = 0.0;

#pragma unroll 1
  for (int t = 0; t < TT; ++t) {
    uint32_t bits = src[(size_t)t * BB];

#pragma unroll
    for (int o = 0; o < 16; ++o) {
      double sub = (m4[o] > 1.0) ? 1.0 : 0.0;
      m4[o] = 0.9 * m4[o] - sub;
    }
    {
      const double* col = W4T;
      uint32_t b = bits;
      for (int k = 0; k < 32; ++k) {
        double s = (double)(b & 1u);
        b >>= 1;
#pragma unroll
        for (int o = 0; o < 16; ++o) m4[o] = fma(s, col[o], m4[o]);
        col += 16;
      }
    }
    uint32_t msk4 = 0u;
#pragma unroll
    for (int o = 0; o < 16; ++o) msk4 |= (m4[o] > 1.0) ? (1u << o) : 0u;

#pragma unroll
    for (int o = 0; o < 6; ++o) {
      double sub = (m5[o] > 1.0) ? 1.0 : 0.0;
      m5[o] = 0.9 * m5[o] - sub;
    }
    {
      const double* col = W5T;
      uint32_t b = msk4;
      for (int k = 0; k < 16; ++k) {
        double s = (double)(b & 1u);
        b >>= 1;
#pragma unroll
        for (int o = 0; o < 6; ++o) m5[o] = fma(s, col[o], m5[o]);
        col += 6;
      }
    }

    float ov[6];
#pragma unroll
    for (int o = 0; o < 6; ++o) ov[o] = (m5[o] > 1.0) ? 1.0f : 0.0f;
    float* op = out + ((size_t)t * BB + e) * 6;
    ((float2*)op)[0] = make_float2(ov[0], ov[1]);
    ((float2*)op)[1] = make_float2(ov[2], ov[3]);
    ((float2*)op)[2] = make_float2(ov[4], ov[5]);
  }
}

// ---------------- fallback: monolithic kernel (ws too small; new layout) ----------------

__global__ __launch_bounds__(256, 1) void snn_f64(const float* __restrict__ x,
                                                  const double* __restrict__ Wd,
                                                  float* __restrict__ out) {
  const int e = blockIdx.x * blockDim.x + threadIdx.x;

  double m1[64], m2[32], m3[32], m4[16], m5[6];
#pragma unroll
  for (int o = 0; o < 64; ++o) m1[o] = 0.0;
#pragma unroll
  for (int o = 0; o < 32; ++o) m2[o] = 0.0;
#pragma unroll
  for (int o = 0; o < 32; ++o) m3[o] = 0.0;
#pragma unroll
  for (int o = 0; o < 16; ++o) m4[o] = 0.0;
#pragma unroll
  for (int o = 0; o < 6; ++o) m5[o] = 0.0;

#pragma unroll 1
  for (int t = 0; t < TT; ++t) {
    const float* xp = x + ((size_t)t * BB + e) * 10;
    float xv[10];
#pragma unroll
    for (int i = 0; i < 5; ++i) {
      float2 f = ((const float2*)xp)[i];
      xv[2 * i] = f.x; xv[2 * i + 1] = f.y;
    }
#pragma unroll
    for (int o = 0; o < 64; ++o) {
      double sub = (m1[o] > 1.0) ? 1.0 : 0.0;
      m1[o] = 0.9 * m1[o] - sub;
    }
#pragma unroll
    for (int p = 0; p < 2; ++p) {
#pragma unroll
      for (int k = 0; k < 10; ++k) {
        double s = (double)xv[k];
        const double* col = Wd + p * 320 + k * 32;
#pragma unroll
        for (int o = 0; o < 32; ++o) m1[p * 32 + o] = fma(s, col[o], m1[p * 32 + o]);
      }
    }
    unsigned long long msk1 = 0ull;
#pragma unroll
    for (int o = 0; o < 64; ++o) msk1 |= (m1[o] > 1.0) ? (1ull << o) : 0ull;

#pragma unroll
    for (int o = 0; o < 32; ++o) {
      double sub = (m2[o] > 1.0) ? 1.0 : 0.0;
      m2[o] = 0.9 * m2[o] - sub;
    }
    {
      unsigned long long b = msk1;
      const double* col = Wd + OFF_W2T;
      for (int k = 0; k < 64; ++k) {
        double s = (double)(unsigned int)(b & 1ull);
        b >>= 1;
#pragma unroll
        for (int o = 0; o < 32; ++o) m2[o] = fma(s, col[o], m2[o]);
        col += 32;
      }
    }
    unsigned int msk2 = 0u;
#pragma unroll
    for (int o = 0; o < 32; ++o) msk2 |= (m2[o] > 1.0) ? (1u << o) : 0u;

#pragma unroll
    for (int o = 0; o < 32; ++o) {
      double sub = (m3[o] > 1.0) ? 1.0 : 0.0;
      m3[o] = 0.9 * m3[o] - sub;
    }
#pragma unroll
    for (int p = 0; p < 2; ++p) {
      unsigned int b = msk2;
      const double* col = Wd + OFF_W3P + p * 512;
      for (int k = 0; k < 32; ++k) {
        double s = (double)(b & 1u);
        b >>= 1;
#pragma unroll
        for (int o = 0; o < 16; ++o) m3[p * 16 + o] = fma(s, col[o], m3[p * 16 + o]);
        col += 16;
      }
    }
    unsigned int msk3 = 0u;
#pragma unroll
    for (int o = 0; o < 32; ++o) msk3 |= (m3[o] > 1.0) ? (1u << o) : 0u;

#pragma unroll
    for (int o = 0; o < 16; ++o) {
      double sub = (m4[o] > 1.0) ? 1.0 : 0.0;
      m4[o] = 0.9 * m4[o] - sub;
    }
    {
      unsigned int b = msk3;
      const double* col = Wd + OFF_W4T;
      for (int k = 0; k < 32; ++k) {
        double s = (double)(b & 1u);
        b >>= 1;
#pragma unroll
        for (int o = 0; o < 16; ++o) m4[o] = fma(s, col[o], m4[o]);
        col += 16;
      }
    }
    unsigned int msk4 = 0u;
#pragma unroll
    for (int o = 0; o < 16; ++o) msk4 |= (m4[o] > 1.0) ? (1u << o) : 0u;

#pragma unroll
    for (int o = 0; o < 6; ++o) {
      double sub = (m5[o] > 1.0) ? 1.0 : 0.0;
      m5[o] = 0.9 * m5[o] - sub;
    }
    {
      unsigned int b = msk4;
      const double* col = Wd + OFF_W5T;
      for (int k = 0; k < 16; ++k) {
        double s = (double)(b & 1u);
        b >>= 1;
#pragma unroll
        for (int o = 0; o < 6; ++o) m5[o] = fma(s, col[o], m5[o]);
        col += 6;
      }
    }

    float ov[6];
#pragma unroll
    for (int o = 0; o < 6; ++o) ov[o] = (m5[o] > 1.0) ? 1.0f : 0.0f;
    float* op = out + ((size_t)t * BB + e) * 6;
    ((float2*)op)[0] = make_float2(ov[0], ov[1]);
    ((float2*)op)[1] = make_float2(ov[2], ov[3]);
    ((float2*)op)[2] = make_float2(ov[4], ov[5]);
  }
}

extern "C" void kernel_launch(void* const* d_in, const int* in_sizes, int n_in,
                              void* d_out, int out_size, void* d_ws, size_t ws_size,
                              hipStream_t stream) {
  const float* x  = (const float*)d_in[0];
  const float* W1 = (const float*)d_in[1];
  const float* W2 = (const float*)d_in[2];
  const float* W3 = (const float*)d_in[3];
  const float* W4 = (const float*)d_in[4];
  const float* W5 = (const float*)d_in[5];
  float* out = (float*)d_out;
  double* Wd = (double*)d_ws;

  prep_weights<<<17, 256, 0, stream>>>(W1, W2, W3, W4, W5, Wd);

  if (ws_size >= WS_NEEDED) {
    char* base = (char*)d_ws;
    uint32_t* P1 = (uint32_t*)(base + WS_MASK_BASE);   // u32[TT][BB][2]
    uint32_t* P2 = (uint32_t*)(base + P2_OFFSET);      // u32[TT][BB]
    uint16_t* P3 = (uint16_t*)(base + WS_MASK_BASE);   // u16[TT][BB][2], aliases P1
    snn_l1<<<2048, 256, 0, stream>>>(x, Wd, P1);
    snn_l2<<<1024, 256, 0, stream>>>(Wd, P1, P2);
    snn_l3<<<2048, 256, 0, stream>>>(Wd, P2, P3);
    snn_l45<<<1024, 256, 0, stream>>>(Wd, (const uint32_t*)P3, out);
  } else {
    snn_f64<<<BB / 256, 256, 0, stream>>>(x, Wd, out);
  }
}